// Round 3
// baseline (675.391 us; speedup 1.0000x reference)
//
#include <hip/hip_runtime.h>
#include <math.h>

#define NTOK 16384
#define HDIM 4096
#define NEXP 64
#define SPLITS 8
#define KRANGE (HDIM / SPLITS)  // 512 K per block
#define KC 32                   // K chunk staged in LDS
#define NCHUNK (KRANGE / KC)    // 16
#define TOKTILE 256             // tokens per block

// LDS in float4 granules (16 B). Row-major, 8 granules (= 32 K floats) per row.
// XOR swizzle phys_col_granule = col ^ ((row>>3)&7), applied on BOTH the
// ds_write (reg staging) and the ds_read (fragment fetch) — an involution.
// Makes the 8-row-apart fragment reads hit 8 distinct 4-bank windows.
#define XGRAN 2048              // 256 rows * 8 granules
#define WGRAN 512               // 64 rows * 8
#define BUFGRAN (XGRAN + WGRAN) // 2560 granules = 40 KB (single buffer)

// Register-tiled fp32 GEMM. Block: 256 tok x 64 exp x K=512 (split-K=8).
// 256 threads (4 waves), 8x8 thread tile: per 4-k group, 16 broadcast
// ds_read_b128 feed 256 FMA instrs. Staging: global->reg (issued before the
// FMA phase, latency hidden) -> swizzled ds_write_b128 after the read-done
// barrier. Grid 512 = exactly 2 blocks/CU.
__global__ __launch_bounds__(256, 2) void gemm_tile(const float* __restrict__ x,
                                                    const float* __restrict__ W,
                                                    float* __restrict__ partial) {
  __shared__ __align__(16) float4 lds4[BUFGRAN];
  const int bid = (int)blockIdx.x;
  const int tile = bid >> 3;
  const int split = bid & 7;
  const int tok0 = tile * TOKTILE;
  const int kbase = split * KRANGE;
  const int t = (int)threadIdx.x;
  const int tg = t >> 3;  // 0..31: tokens tg*8 .. tg*8+7
  const int eg = t & 7;   // 0..7 : experts eg*8 .. eg*8+7

  // staging geometry: instr s covers rows s*32 + (t>>3), col granule t&7
  const int srow = t >> 3;      // 0..31
  const int scg = t & 7;        // logical col granule
  const float* xsrc[8];
  int xdst[8];  // LDS granule index (swizzled)
#pragma unroll
  for (int s = 0; s < 8; ++s) {
    const int row = s * 32 + srow;
    xsrc[s] = x + (size_t)(tok0 + row) * HDIM + kbase + scg * 4;
    xdst[s] = row * 8 + (scg ^ ((row >> 3) & 7));
  }
  const float* wsrc[2];
  int wdst[2];
#pragma unroll
  for (int s = 0; s < 2; ++s) {
    const int row = s * 32 + srow;
    wsrc[s] = W + (size_t)row * HDIM + kbase + scg * 4;
    wdst[s] = XGRAN + row * 8 + (scg ^ ((row >> 3) & 7));
  }

  float acc[8][8];
#pragma unroll
  for (int i = 0; i < 8; ++i)
#pragma unroll
    for (int j = 0; j < 8; ++j) acc[i][j] = 0.0f;

  // preload chunk 0 into regs
  float4 xa[8], wa[2];
#pragma unroll
  for (int s = 0; s < 8; ++s) xa[s] = *(const float4*)xsrc[s];
#pragma unroll
  for (int s = 0; s < 2; ++s) wa[s] = *(const float4*)wsrc[s];

  const float4* xs4 = lds4 + tg * 64;           // token rows tg*8..tg*8+7
  const float4* ws4 = lds4 + XGRAN + eg * 64;   // expert rows eg*8..eg*8+7
  const int xsw = tg & 7;

#pragma unroll 1
  for (int c = 0; c < NCHUNK; ++c) {
    __syncthreads();  // all waves done reading previous chunk (no-op at c=0)
#pragma unroll
    for (int s = 0; s < 8; ++s) lds4[xdst[s]] = xa[s];  // stride-1 b128, free
#pragma unroll
    for (int s = 0; s < 2; ++s) lds4[wdst[s]] = wa[s];
    __syncthreads();  // chunk c visible

    if (c + 1 < NCHUNK) {  // issue next-chunk loads; latency hides under FMA
#pragma unroll
      for (int s = 0; s < 8; ++s) xa[s] = *(const float4*)(xsrc[s] + (c + 1) * KC);
#pragma unroll
      for (int s = 0; s < 2; ++s) wa[s] = *(const float4*)(wsrc[s] + (c + 1) * KC);
    }

#pragma unroll
    for (int k4 = 0; k4 < 8; ++k4) {
      float4 xf[8], wf[8];
#pragma unroll
      for (int i = 0; i < 8; ++i) xf[i] = xs4[i * 8 + (k4 ^ xsw)];  // 8-way bcast
#pragma unroll
      for (int j = 0; j < 8; ++j) wf[j] = ws4[j * 8 + (k4 ^ eg)];   // 8-way bcast
#pragma unroll
      for (int i = 0; i < 8; ++i)
#pragma unroll
        for (int j = 0; j < 8; ++j) {
          acc[i][j] = fmaf(xf[i].x, wf[j].x, acc[i][j]);
          acc[i][j] = fmaf(xf[i].y, wf[j].y, acc[i][j]);
          acc[i][j] = fmaf(xf[i].z, wf[j].z, acc[i][j]);
          acc[i][j] = fmaf(xf[i].w, wf[j].w, acc[i][j]);
        }
    }
  }

  // partial[split][tok][exp]: wave-per-token topk reads 64 contiguous floats
#pragma unroll
  for (int i = 0; i < 8; ++i) {
    const int tok = tok0 + tg * 8 + i;
    float* dst = partial + ((size_t)split * NTOK + tok) * NEXP + eg * 8;
    float4 o0 = {acc[i][0], acc[i][1], acc[i][2], acc[i][3]};
    float4 o1 = {acc[i][4], acc[i][5], acc[i][6], acc[i][7]};
    *(float4*)dst = o0;
    *(float4*)(dst + 4) = o1;
  }
}

// ---------------- split-reduce + top-8 + softmax + usage counts ----------------
// Wave per token: lane = expert. 8 rounds of butterfly argmax (lower index
// wins ties -> matches lax.top_k stable ordering). Replaces the serial
// 64x8 insertion sort that ran at 1 wave/CU occupancy.
__global__ __launch_bounds__(256) void topk_kernel(const float* __restrict__ partial,
                                                   float* __restrict__ out_scores,
                                                   float* __restrict__ out_idx,
                                                   unsigned int* __restrict__ counts) {
  __shared__ unsigned int lcnt[64];
  const int t = (int)threadIdx.x;
  if (t < 64) lcnt[t] = 0u;
  __syncthreads();

  const int n = (int)blockIdx.x * 4 + (t >> 6);
  const int lane = t & 63;

  float lg = 0.0f;
#pragma unroll
  for (int sp = 0; sp < SPLITS; ++sp)
    lg += partial[((size_t)sp * NTOK + n) * NEXP + lane];

  float v = lg;
  const int vi = lane;
  float sv[8];
  int si[8];
#pragma unroll
  for (int j = 0; j < 8; ++j) {
    float bv = v;
    int bi = vi;
#pragma unroll
    for (int off = 32; off > 0; off >>= 1) {
      float ov = __shfl_xor(bv, off);
      int oi = __shfl_xor(bi, off);
      if (ov > bv || (ov == bv && oi < bi)) { bv = ov; bi = oi; }
    }
    sv[j] = bv;  // all lanes converge to the same (bv, bi)
    si[j] = bi;
    if (vi == bi) v = -INFINITY;  // remove winner for next round
  }

  float ex[8], sum = 0.0f;
#pragma unroll
  for (int j = 0; j < 8; ++j) { ex[j] = expf(sv[j] - sv[0]); sum += ex[j]; }
  const float inv = 1.0f / sum;

  if (lane < 8) {
    float me = ex[0];
    int mi = si[0];
#pragma unroll
    for (int j = 1; j < 8; ++j)
      if (lane == j) { me = ex[j]; mi = si[j]; }  // const-indexed selects
    out_scores[(size_t)n * 8 + lane] = me * inv;
    out_idx[(size_t)n * 8 + lane] = (float)mi;
    atomicAdd(&lcnt[mi], 1u);
  }
  __syncthreads();
  if (t < 64) atomicAdd(&counts[t], lcnt[t]);
}

// ---------------- load-balance loss ----------------
__global__ __launch_bounds__(64) void loss_kernel(const unsigned int* __restrict__ counts,
                                                  float* __restrict__ out_loss) {
  const int e = (int)threadIdx.x;
  double d = (double)counts[e] / (double)NTOK - 1.0 / 64.0;
  double sq = d * d;
#pragma unroll
  for (int off = 32; off > 0; off >>= 1) sq += __shfl_down(sq, off);
  if (e == 0) *out_loss = (float)(0.01 * sq);
}

extern "C" void kernel_launch(void* const* d_in, const int* in_sizes, int n_in,
                              void* d_out, int out_size, void* d_ws, size_t ws_size,
                              hipStream_t stream) {
  const float* x = (const float*)d_in[0];  // [16384][4096] fp32
  const float* W = (const float*)d_in[1];  // [64][4096] fp32

  float* out = (float*)d_out;
  float* scores = out;                    // [16384][8]
  float* idxf = out + (size_t)NTOK * 8;   // [16384][8]
  float* loss = out + (size_t)NTOK * 16;  // scalar

  // ws: [0,256) counts; [256, 256+32MB) split partials fp32 [8][16384][64]
  unsigned int* counts = (unsigned int*)d_ws;
  float* partial = (float*)((char*)d_ws + 256);

  hipMemsetAsync(d_ws, 0, 256, stream);
  gemm_tile<<<(NTOK / TOKTILE) * SPLITS, 256, 0, stream>>>(x, W, partial);
  topk_kernel<<<NTOK / 4, 256, 0, stream>>>(partial, scores, idxf, counts);
  loss_kernel<<<1, 64, 0, stream>>>(counts, loss);
}